// Round 1
// baseline (181.082 us; speedup 1.0000x reference)
//
#include <hip/hip_runtime.h>

#define S_ELEM 524288   // N*K*C = 128*64*64
#define ROWS   8192     // N*K

typedef __attribute__((ext_vector_type(4))) float  f32x4;
typedef __attribute__((ext_vector_type(8))) __bf16 bf16x8;

__device__ __forceinline__ float fast_tanh(float x) {
    float ax = __builtin_fabsf(x);
    float t  = __expf(-2.0f * ax);
    float r  = (1.0f - t) * __builtin_amdgcn_rcpf(1.0f + t);
    return __builtin_copysignf(r, x);
}
__device__ __forceinline__ float fast_sigmoid(float x) {
    return __builtin_amdgcn_rcpf(1.0f + __expf(-x));
}

// 4x4 register-tile fp32 GEMM step over K=64 from LDS.
// A is stored transposed: A[k*68 + row]; B is B[k*68 + col].
__device__ __forceinline__ void gemm_tile(const float* A, const float* B,
                                          int r0, int c0, float acc[4][4]) {
#pragma unroll 8
    for (int k = 0; k < 64; ++k) {
        f32x4 a = *(const f32x4*)(A + k * 68 + r0);
        f32x4 b = *(const f32x4*)(B + k * 68 + c0);
#pragma unroll
        for (int i = 0; i < 4; ++i)
#pragma unroll
            for (int j = 0; j < 4; ++j)
                acc[i][j] = __builtin_fmaf(a[i], b[j], acc[i][j]);
    }
}

// ---------------------------------------------------------------------------
// prep: h = x@W_lin + b ; P/Q/Pg/Qg (biases folded into P/Pg) ; um (gated unary)
// grid 128 blocks x 256 threads; block handles 64 rows of the 8192.
// ---------------------------------------------------------------------------
__global__ __launch_bounds__(256) void prep_kernel(
    const float* __restrict__ x,
    const float* __restrict__ W_lin, const float* __restrict__ b_lin,
    const float* __restrict__ Wu1,  const float* __restrict__ bu1,
    const float* __restrict__ Wu2,  const float* __restrict__ bu2,
    const float* __restrict__ Wug1, const float* __restrict__ bug1,
    const float* __restrict__ Wug2, const float* __restrict__ bug2,
    const float* __restrict__ Wb1,  const float* __restrict__ bb1,
    const float* __restrict__ Wbg1, const float* __restrict__ bbg1,
    float* __restrict__ P, float* __restrict__ Q,
    float* __restrict__ Pg, float* __restrict__ Qg,
    float* __restrict__ um)
{
    __shared__ float As[64 * 68];   // x transposed, later t1u transposed
    __shared__ float Hs[64 * 68];   // h transposed, later t1g transposed
    __shared__ float Bs[64 * 68];   // current weight tile

    int tid  = threadIdx.x;
    int row0 = blockIdx.x * 64;
    int r0   = (tid >> 4) * 4;
    int c0   = (tid & 15) * 4;

    for (int idx = tid; idx < 4096; idx += 256) {
        int r = idx >> 6, k = idx & 63;
        As[k * 68 + r] = x[(size_t)(row0 + r) * 64 + k];
        Bs[(idx >> 6) * 68 + (idx & 63)] = W_lin[idx];
    }
    __syncthreads();

    float acc[4][4];
#pragma unroll
    for (int i = 0; i < 4; ++i)
#pragma unroll
        for (int j = 0; j < 4; ++j) acc[i][j] = b_lin[c0 + j];
    gemm_tile(As, Bs, r0, c0, acc);
    // store h transposed for subsequent GEMMs
#pragma unroll
    for (int i = 0; i < 4; ++i)
#pragma unroll
        for (int j = 0; j < 4; ++j) Hs[(c0 + j) * 68 + (r0 + i)] = acc[i][j];
    __syncthreads();

    // chunks 0..3: P, Q, Pg, Qg
    const float* Wtab[4] = {Wb1, Wb1 + 4096, Wbg1, Wbg1 + 4096};
    const float* btab[4] = {bb1, nullptr, bbg1, nullptr};
    float*       otab[4] = {P, Q, Pg, Qg};
#pragma unroll
    for (int ch = 0; ch < 4; ++ch) {
        for (int idx = tid; idx < 4096; idx += 256)
            Bs[(idx >> 6) * 68 + (idx & 63)] = Wtab[ch][idx];
        __syncthreads();
#pragma unroll
        for (int i = 0; i < 4; ++i)
#pragma unroll
            for (int j = 0; j < 4; ++j)
                acc[i][j] = btab[ch] ? btab[ch][c0 + j] : 0.0f;
        gemm_tile(Hs, Bs, r0, c0, acc);
        float* op = otab[ch];
#pragma unroll
        for (int i = 0; i < 4; ++i) {
            f32x4 v;
#pragma unroll
            for (int j = 0; j < 4; ++j) v[j] = acc[i][j];
            *(f32x4*)(op + (size_t)(row0 + r0 + i) * 64 + c0) = v;
        }
        __syncthreads();
    }

    // chunk 4: t1u = tanh(h@Wu1 + bu1) -> As region (transposed)
    for (int idx = tid; idx < 4096; idx += 256)
        Bs[(idx >> 6) * 68 + (idx & 63)] = Wu1[idx];
    __syncthreads();
#pragma unroll
    for (int i = 0; i < 4; ++i)
#pragma unroll
        for (int j = 0; j < 4; ++j) acc[i][j] = bu1[c0 + j];
    gemm_tile(Hs, Bs, r0, c0, acc);
#pragma unroll
    for (int i = 0; i < 4; ++i)
#pragma unroll
        for (int j = 0; j < 4; ++j)
            As[(c0 + j) * 68 + (r0 + i)] = fast_tanh(acc[i][j]);
    __syncthreads();

    // chunk 5: t1g = tanh(h@Wug1 + bug1) -> regs, then overwrite Hs
    for (int idx = tid; idx < 4096; idx += 256)
        Bs[(idx >> 6) * 68 + (idx & 63)] = Wug1[idx];
    __syncthreads();
    float tg[4][4];
#pragma unroll
    for (int i = 0; i < 4; ++i)
#pragma unroll
        for (int j = 0; j < 4; ++j) tg[i][j] = bug1[c0 + j];
    gemm_tile(Hs, Bs, r0, c0, tg);
    __syncthreads();   // all reads of Hs done before overwrite
#pragma unroll
    for (int i = 0; i < 4; ++i)
#pragma unroll
        for (int j = 0; j < 4; ++j)
            Hs[(c0 + j) * 68 + (r0 + i)] = fast_tanh(tg[i][j]);

    // chunk 6: u = t1u@Wu2 + bu2
    for (int idx = tid; idx < 4096; idx += 256)
        Bs[(idx >> 6) * 68 + (idx & 63)] = Wu2[idx];
    __syncthreads();
    float ua[4][4];
#pragma unroll
    for (int i = 0; i < 4; ++i)
#pragma unroll
        for (int j = 0; j < 4; ++j) ua[i][j] = bu2[c0 + j];
    gemm_tile(As, Bs, r0, c0, ua);
    __syncthreads();

    // chunk 7: g = t1g@Wug2 + bug2 ; um = u * sigmoid(g)
    for (int idx = tid; idx < 4096; idx += 256)
        Bs[(idx >> 6) * 68 + (idx & 63)] = Wug2[idx];
    __syncthreads();
    float ga[4][4];
#pragma unroll
    for (int i = 0; i < 4; ++i)
#pragma unroll
        for (int j = 0; j < 4; ++j) ga[i][j] = bug2[c0 + j];
    gemm_tile(Hs, Bs, r0, c0, ga);
#pragma unroll
    for (int i = 0; i < 4; ++i) {
        f32x4 v;
#pragma unroll
        for (int j = 0; j < 4; ++j)
            v[j] = ua[i][j] * fast_sigmoid(ga[i][j]);
        *(f32x4*)(um + (size_t)(row0 + r0 + i) * 64 + c0) = v;
    }
}

// ---------------------------------------------------------------------------
// swizzle Wb2 / Wbg2 into MFMA B-fragment order (bf16), coalesced for binary_kernel
// layout: [p][cc][kk][quad][l16][jj]
// ---------------------------------------------------------------------------
__global__ __launch_bounds__(256) void swizzle_kernel(
    const float* __restrict__ Wb2, const float* __restrict__ Wbg2,
    __bf16* __restrict__ wfrag)
{
    int idx = blockIdx.x * 256 + threadIdx.x;   // 0..8191
    const float* W = (idx < 4096) ? Wb2 : Wbg2;
    int r   = idx & 4095;
    int jj  = r & 7;
    int l16 = (r >> 3) & 15;
    int qd  = (r >> 7) & 3;
    int kk  = (r >> 9) & 1;
    int cc  = (r >> 10) & 3;
    int k   = kk * 32 + qd * 8 + jj;
    int col = cc * 16 + l16;
    wfrag[idx] = (__bf16)W[k * 64 + col];
}

// ---------------------------------------------------------------------------
// binary path: block = (i-chunk of 8, n). 4 waves, wave w owns j rows 16w..16w+15.
// A[j][c] = tanh(P[n,j,c] + Q[n,i,c]) built in-register, MFMA 16x16x32 bf16.
// acc[j][c] += msg * sigmoid(gate), summed over the 8 i's; partial per chunk.
// ---------------------------------------------------------------------------
__global__ __launch_bounds__(256) void binary_kernel(
    const float* __restrict__ P,  const float* __restrict__ Q,
    const float* __restrict__ Pg, const float* __restrict__ Qg,
    const float* __restrict__ bb2, const float* __restrict__ bbg2,
    const __bf16* __restrict__ wfrag,
    float* __restrict__ part, int atomic_mode)
{
    __shared__ float Ps[64 * 68], Pgs[64 * 68];
    __shared__ float Qs[8 * 64], Qgs[8 * 64];

    int tid = threadIdx.x;
    int w   = tid >> 6;
    int l   = tid & 63;
    int qd  = l >> 4;
    int l16 = l & 15;
    int n   = blockIdx.y;
    int i0  = blockIdx.x * 8;

    for (int idx = tid; idx < 4096; idx += 256) {
        int j = idx >> 6, c = idx & 63;
        Ps[j * 68 + c]  = P[(size_t)n * 4096 + idx];
        Pgs[j * 68 + c] = Pg[(size_t)n * 4096 + idx];
    }
    for (int idx = tid; idx < 512; idx += 256) {
        Qs[idx]  = Q[(size_t)n * 4096 + i0 * 64 + idx];
        Qgs[idx] = Qg[(size_t)n * 4096 + i0 * 64 + idx];
    }

    // B fragments (resident in registers for the whole block)
    const bf16x8* wf = (const bf16x8*)wfrag;
    bf16x8 bwm[4][2], bwg[4][2];
#pragma unroll
    for (int cc = 0; cc < 4; ++cc)
#pragma unroll
        for (int kk = 0; kk < 2; ++kk) {
            bwm[cc][kk] = wf[cc * 128 + kk * 64 + qd * 16 + l16];
            bwg[cc][kk] = wf[512 + cc * 128 + kk * 64 + qd * 16 + l16];
        }
    float bim[4], big[4];
#pragma unroll
    for (int cc = 0; cc < 4; ++cc) {
        bim[cc] = bb2[cc * 16 + l16];
        big[cc] = bbg2[cc * 16 + l16];
    }
    float acc[4][4];
#pragma unroll
    for (int cc = 0; cc < 4; ++cc)
#pragma unroll
        for (int r = 0; r < 4; ++r) acc[cc][r] = 0.0f;
    __syncthreads();

    const float* prm = Ps  + (16 * w + l16) * 68;
    const float* prg = Pgs + (16 * w + l16) * 68;

    for (int ii = 0; ii < 8; ++ii) {
        const float* qm = Qs  + ii * 64;
        const float* qg = Qgs + ii * 64;
        bf16x8 am[2], ag[2];
#pragma unroll
        for (int kk = 0; kk < 2; ++kk) {
            int cb = kk * 32 + qd * 8;
            f32x4 pa = *(const f32x4*)(prm + cb);
            f32x4 pb = *(const f32x4*)(prm + cb + 4);
            f32x4 qa = *(const f32x4*)(qm + cb);
            f32x4 qb = *(const f32x4*)(qm + cb + 4);
            f32x4 ga = *(const f32x4*)(prg + cb);
            f32x4 gb = *(const f32x4*)(prg + cb + 4);
            f32x4 ha = *(const f32x4*)(qg + cb);
            f32x4 hb = *(const f32x4*)(qg + cb + 4);
#pragma unroll
            for (int t = 0; t < 4; ++t) {
                am[kk][t]     = (__bf16)fast_tanh(pa[t] + qa[t]);
                am[kk][t + 4] = (__bf16)fast_tanh(pb[t] + qb[t]);
                ag[kk][t]     = (__bf16)fast_tanh(ga[t] + ha[t]);
                ag[kk][t + 4] = (__bf16)fast_tanh(gb[t] + hb[t]);
            }
        }
#pragma unroll
        for (int cc = 0; cc < 4; ++cc) {
            f32x4 d = {bim[cc], bim[cc], bim[cc], bim[cc]};
            d = __builtin_amdgcn_mfma_f32_16x16x32_bf16(am[0], bwm[cc][0], d, 0, 0, 0);
            d = __builtin_amdgcn_mfma_f32_16x16x32_bf16(am[1], bwm[cc][1], d, 0, 0, 0);
            f32x4 e = {big[cc], big[cc], big[cc], big[cc]};
            e = __builtin_amdgcn_mfma_f32_16x16x32_bf16(ag[0], bwg[cc][0], e, 0, 0, 0);
            e = __builtin_amdgcn_mfma_f32_16x16x32_bf16(ag[1], bwg[cc][1], e, 0, 0, 0);
#pragma unroll
            for (int r = 0; r < 4; ++r)
                acc[cc][r] += d[r] * fast_sigmoid(e[r]);
        }
    }

    float* dst = part + (atomic_mode ? (size_t)0 : (size_t)blockIdx.x * S_ELEM)
                 + (size_t)n * 4096;
#pragma unroll
    for (int cc = 0; cc < 4; ++cc)
#pragma unroll
        for (int r = 0; r < 4; ++r) {
            int jo = 16 * w + qd * 4 + r;
            int co = cc * 16 + l16;
            if (atomic_mode) atomicAdd(dst + jo * 64 + co, acc[cc][r]);
            else             dst[jo * 64 + co] = acc[cc][r];
        }
}

// ---------------------------------------------------------------------------
// finalize: out = um + (sum of partials) / 63
// ---------------------------------------------------------------------------
__global__ __launch_bounds__(256) void finalize_kernel(
    const float* __restrict__ um, const float* __restrict__ part,
    float* __restrict__ out, int nchunks)
{
    int i = blockIdx.x * 256 + threadIdx.x;   // 0..131071 (float4 units)
    const f32x4* u4 = (const f32x4*)um;
    const f32x4* p4 = (const f32x4*)part;
    f32x4* o4 = (f32x4*)out;
    f32x4 s = {0.0f, 0.0f, 0.0f, 0.0f};
    for (int ch = 0; ch < nchunks; ++ch)
        s += p4[(size_t)ch * 131072 + i];
    o4[i] = u4[i] + s * (1.0f / 63.0f);
}

extern "C" void kernel_launch(void* const* d_in, const int* in_sizes, int n_in,
                              void* d_out, int out_size, void* d_ws, size_t ws_size,
                              hipStream_t stream)
{
    (void)in_sizes; (void)n_in; (void)out_size;
    const float* x     = (const float*)d_in[0];
    const float* W_lin = (const float*)d_in[1];
    const float* b_lin = (const float*)d_in[2];
    const float* Wu1   = (const float*)d_in[3];
    const float* bu1   = (const float*)d_in[4];
    const float* Wu2   = (const float*)d_in[5];
    const float* bu2   = (const float*)d_in[6];
    const float* Wug1  = (const float*)d_in[7];
    const float* bug1  = (const float*)d_in[8];
    const float* Wug2  = (const float*)d_in[9];
    const float* bug2  = (const float*)d_in[10];
    const float* Wb1   = (const float*)d_in[11];
    const float* bb1   = (const float*)d_in[12];
    const float* Wb2   = (const float*)d_in[13];
    const float* bb2   = (const float*)d_in[14];
    const float* Wbg1  = (const float*)d_in[15];
    const float* bbg1  = (const float*)d_in[16];
    const float* Wbg2  = (const float*)d_in[17];
    const float* bbg2  = (const float*)d_in[18];

    float*  ws    = (float*)d_ws;
    __bf16* wfrag = (__bf16*)ws;             // 8192 bf16 = 16 KB = 4096 floats
    float*  base  = ws + 4096;
    float*  P  = base;
    float*  Q  = base + (size_t)S_ELEM;
    float*  Pg = base + 2 * (size_t)S_ELEM;
    float*  Qg = base + 3 * (size_t)S_ELEM;
    float*  um = base + 4 * (size_t)S_ELEM;
    float*  part = base + 5 * (size_t)S_ELEM;

    size_t need_full = (4096 + 13 * (size_t)S_ELEM) * 4;
    int atomic_mode = (ws_size >= need_full) ? 0 : 1;

    hipLaunchKernelGGL(prep_kernel, dim3(128), dim3(256), 0, stream,
        x, W_lin, b_lin, Wu1, bu1, Wu2, bu2, Wug1, bug1, Wug2, bug2,
        Wb1, bb1, Wbg1, bbg1, P, Q, Pg, Qg, um);
    hipLaunchKernelGGL(swizzle_kernel, dim3(32), dim3(256), 0, stream,
        Wb2, Wbg2, wfrag);
    if (atomic_mode)
        hipMemsetAsync(part, 0, (size_t)S_ELEM * 4, stream);
    hipLaunchKernelGGL(binary_kernel, dim3(8, 128), dim3(256), 0, stream,
        P, Q, Pg, Qg, bb2, bbg2, wfrag, part, atomic_mode);
    hipLaunchKernelGGL(finalize_kernel, dim3(512), dim3(256), 0, stream,
        um, part, (float*)d_out, atomic_mode ? 1 : 8);
}

// Round 2
// 152.330 us; speedup vs baseline: 1.1887x; 1.1887x over previous
//
#include <hip/hip_runtime.h>

#define S_ELEM 524288   // N*K*C = 128*64*64

typedef __attribute__((ext_vector_type(4))) float    f32x4;
typedef __attribute__((ext_vector_type(8))) _Float16 f16x8;

__device__ __forceinline__ float rcp_f(float x) { return __builtin_amdgcn_rcpf(x); }
__device__ __forceinline__ float fast_sigmoid(float x) {
    return rcp_f(1.0f + __expf(-x));
}
// exact-formula tanh (used in prep only, off the hot path)
__device__ __forceinline__ float tanh_exp(float x) {
    return 1.0f - 2.0f * rcp_f(__expf(2.0f * x) + 1.0f);
}

// 4x4 register-tile fp32 GEMM over K=64 from LDS.
// A transposed: A[k*68 + row]; B: B[k*68 + col].
__device__ __forceinline__ void gemm_tile(const float* A, const float* B,
                                          int r0, int c0, float acc[4][4]) {
#pragma unroll 8
    for (int k = 0; k < 64; ++k) {
        f32x4 a = *(const f32x4*)(A + k * 68 + r0);
        f32x4 b = *(const f32x4*)(B + k * 68 + c0);
#pragma unroll
        for (int i = 0; i < 4; ++i)
#pragma unroll
            for (int j = 0; j < 4; ++j)
                acc[i][j] = __builtin_fmaf(a[i], b[j], acc[i][j]);
    }
}

// ---------------------------------------------------------------------------
// prep1: h = x @ W_lin + b_lin.  128 blocks x 64 rows.
// ---------------------------------------------------------------------------
__global__ __launch_bounds__(256) void prep1_kernel(
    const float* __restrict__ x, const float* __restrict__ W_lin,
    const float* __restrict__ b_lin, float* __restrict__ h)
{
    __shared__ float As[64 * 68], Bs[64 * 68];
    int tid = threadIdx.x, row0 = blockIdx.x * 64;
    int r0 = (tid >> 4) * 4, c0 = (tid & 15) * 4;

    for (int idx = tid; idx < 4096; idx += 256) {
        int r = idx >> 6, k = idx & 63;
        As[k * 68 + r] = x[(size_t)(row0 + r) * 64 + k];
        Bs[(idx >> 6) * 68 + (idx & 63)] = W_lin[idx];
    }
    __syncthreads();

    float acc[4][4];
#pragma unroll
    for (int i = 0; i < 4; ++i)
#pragma unroll
        for (int j = 0; j < 4; ++j) acc[i][j] = b_lin[c0 + j];
    gemm_tile(As, Bs, r0, c0, acc);
#pragma unroll
    for (int i = 0; i < 4; ++i) {
        f32x4 v;
#pragma unroll
        for (int j = 0; j < 4; ++j) v[j] = acc[i][j];
        *(f32x4*)(h + (size_t)(row0 + r0 + i) * 64 + c0) = v;
    }
}

// ---------------------------------------------------------------------------
// prep2: 6 independent GEMMs from h. grid (128 rowblocks, 6 chunks).
// ch0: EP=exp(2(h@Wb1[:C]+bb1))   ch1: EQ=exp(2(h@Wb1[C:]))
// ch2: EPg=exp(2(h@Wbg1[:C]+bbg1)) ch3: EQg=exp(2(h@Wbg1[C:]))
// ch4: T1u=tanh(h@Wu1+bu1)        ch5: T1g=tanh(h@Wug1+bug1)
// ---------------------------------------------------------------------------
__global__ __launch_bounds__(256) void prep2_kernel(
    const float* __restrict__ h,
    const float* __restrict__ Wb1,  const float* __restrict__ bb1,
    const float* __restrict__ Wbg1, const float* __restrict__ bbg1,
    const float* __restrict__ Wu1,  const float* __restrict__ bu1,
    const float* __restrict__ Wug1, const float* __restrict__ bug1,
    float* __restrict__ EP,  float* __restrict__ EQ,
    float* __restrict__ EPg, float* __restrict__ EQg,
    float* __restrict__ T1u, float* __restrict__ T1g)
{
    __shared__ float Hs[64 * 68], Bs[64 * 68];
    int tid = threadIdx.x, row0 = blockIdx.x * 64;
    int r0 = (tid >> 4) * 4, c0 = (tid & 15) * 4;
    int ch = blockIdx.y;

    const float* W; const float* bias; float* out; int mode;
    switch (ch) {
        case 0:  W = Wb1;         bias = bb1;     out = EP;  mode = 0; break;
        case 1:  W = Wb1 + 4096;  bias = nullptr; out = EQ;  mode = 0; break;
        case 2:  W = Wbg1;        bias = bbg1;    out = EPg; mode = 0; break;
        case 3:  W = Wbg1 + 4096; bias = nullptr; out = EQg; mode = 0; break;
        case 4:  W = Wu1;         bias = bu1;     out = T1u; mode = 1; break;
        default: W = Wug1;        bias = bug1;    out = T1g; mode = 1; break;
    }

    for (int idx = tid; idx < 4096; idx += 256) {
        int r = idx >> 6, k = idx & 63;
        Hs[k * 68 + r] = h[(size_t)(row0 + r) * 64 + k];
        Bs[(idx >> 6) * 68 + (idx & 63)] = W[idx];
    }
    __syncthreads();

    float acc[4][4];
#pragma unroll
    for (int i = 0; i < 4; ++i)
#pragma unroll
        for (int j = 0; j < 4; ++j) acc[i][j] = bias ? bias[c0 + j] : 0.0f;
    gemm_tile(Hs, Bs, r0, c0, acc);
#pragma unroll
    for (int i = 0; i < 4; ++i) {
        f32x4 v;
#pragma unroll
        for (int j = 0; j < 4; ++j) {
            float a = acc[i][j];
            v[j] = (mode == 0) ? __expf(2.0f * a) : tanh_exp(a);
        }
        *(f32x4*)(out + (size_t)(row0 + r0 + i) * 64 + c0) = v;
    }
}

// ---------------------------------------------------------------------------
// prep3: U = T1u@Wu2 + bu2 ; G = T1g@Wug2 + bug2. grid (128, 2).
// ---------------------------------------------------------------------------
__global__ __launch_bounds__(256) void prep3_kernel(
    const float* __restrict__ T1u, const float* __restrict__ Wu2,
    const float* __restrict__ bu2,
    const float* __restrict__ T1g, const float* __restrict__ Wug2,
    const float* __restrict__ bug2,
    float* __restrict__ U, float* __restrict__ G)
{
    __shared__ float As[64 * 68], Bs[64 * 68];
    int tid = threadIdx.x, row0 = blockIdx.x * 64;
    int r0 = (tid >> 4) * 4, c0 = (tid & 15) * 4;
    int ch = blockIdx.y;

    const float* A = ch ? T1g : T1u;
    const float* W = ch ? Wug2 : Wu2;
    const float* bias = ch ? bug2 : bu2;
    float* out = ch ? G : U;

    for (int idx = tid; idx < 4096; idx += 256) {
        int r = idx >> 6, k = idx & 63;
        As[k * 68 + r] = A[(size_t)(row0 + r) * 64 + k];
        Bs[(idx >> 6) * 68 + (idx & 63)] = W[idx];
    }
    __syncthreads();

    float acc[4][4];
#pragma unroll
    for (int i = 0; i < 4; ++i)
#pragma unroll
        for (int j = 0; j < 4; ++j) acc[i][j] = bias[c0 + j];
    gemm_tile(As, Bs, r0, c0, acc);
#pragma unroll
    for (int i = 0; i < 4; ++i) {
        f32x4 v;
#pragma unroll
        for (int j = 0; j < 4; ++j) v[j] = acc[i][j];
        *(f32x4*)(out + (size_t)(row0 + r0 + i) * 64 + c0) = v;
    }
}

// ---------------------------------------------------------------------------
// swizzle Wb2 / Wbg2 into MFMA B-fragment order (fp16)
// layout: [p][cc][kk][quad][l16][jj]
// ---------------------------------------------------------------------------
__global__ __launch_bounds__(256) void swizzle_kernel(
    const float* __restrict__ Wb2, const float* __restrict__ Wbg2,
    _Float16* __restrict__ wfrag)
{
    int idx = blockIdx.x * 256 + threadIdx.x;   // 0..8191
    const float* W = (idx < 4096) ? Wb2 : Wbg2;
    int r   = idx & 4095;
    int jj  = r & 7;
    int l16 = (r >> 3) & 15;
    int qd  = (r >> 7) & 3;
    int kk  = (r >> 9) & 1;
    int cc  = (r >> 10) & 3;
    int k   = kk * 32 + qd * 8 + jj;
    int col = cc * 16 + l16;
    wfrag[idx] = (_Float16)W[k * 64 + col];
}

// ---------------------------------------------------------------------------
// binary path: block = (i-chunk of 8, n). tanh(P+Q) = 1 - 2/(EP*EQ + 1):
// one v_rcp per element, no exp in the hot loop. fp16 MFMA 16x16x32.
// ---------------------------------------------------------------------------
__global__ __launch_bounds__(256) void binary_kernel(
    const float* __restrict__ EP,  const float* __restrict__ EQ,
    const float* __restrict__ EPg, const float* __restrict__ EQg,
    const float* __restrict__ bb2, const float* __restrict__ bbg2,
    const _Float16* __restrict__ wfrag,
    float* __restrict__ part, int atomic_mode)
{
    __shared__ float Ps[64 * 68], Pgs[64 * 68];
    __shared__ float Qs[8 * 64], Qgs[8 * 64];

    int tid = threadIdx.x;
    int w   = tid >> 6;
    int l   = tid & 63;
    int qd  = l >> 4;
    int l16 = l & 15;
    int n   = blockIdx.y;
    int i0  = blockIdx.x * 8;

    for (int idx = tid; idx < 4096; idx += 256) {
        int j = idx >> 6, c = idx & 63;
        Ps[j * 68 + c]  = EP[(size_t)n * 4096 + idx];
        Pgs[j * 68 + c] = EPg[(size_t)n * 4096 + idx];
    }
    for (int idx = tid; idx < 512; idx += 256) {
        Qs[idx]  = EQ[(size_t)n * 4096 + i0 * 64 + idx];
        Qgs[idx] = EQg[(size_t)n * 4096 + i0 * 64 + idx];
    }

    // B fragments + biases, resident for whole block
    const f16x8* wf = (const f16x8*)wfrag;
    f16x8 bwm[4][2], bwg[4][2];
#pragma unroll
    for (int cc = 0; cc < 4; ++cc)
#pragma unroll
        for (int kk = 0; kk < 2; ++kk) {
            bwm[cc][kk] = wf[cc * 128 + kk * 64 + qd * 16 + l16];
            bwg[cc][kk] = wf[512 + cc * 128 + kk * 64 + qd * 16 + l16];
        }
    float bim[4], big[4];
#pragma unroll
    for (int cc = 0; cc < 4; ++cc) {
        bim[cc] = bb2[cc * 16 + l16];
        big[cc] = bbg2[cc * 16 + l16];
    }
    float acc[4][4];
#pragma unroll
    for (int cc = 0; cc < 4; ++cc)
#pragma unroll
        for (int r = 0; r < 4; ++r) acc[cc][r] = 0.0f;
    __syncthreads();

    // hoist loop-invariant EP/EPg row fragments into registers
    const float* prm = Ps  + (16 * w + l16) * 68;
    const float* prg = Pgs + (16 * w + l16) * 68;
    f32x4 pm[4], pg[4];
#pragma unroll
    for (int kk = 0; kk < 2; ++kk) {
        pm[kk * 2]     = *(const f32x4*)(prm + kk * 32 + qd * 8);
        pm[kk * 2 + 1] = *(const f32x4*)(prm + kk * 32 + qd * 8 + 4);
        pg[kk * 2]     = *(const f32x4*)(prg + kk * 32 + qd * 8);
        pg[kk * 2 + 1] = *(const f32x4*)(prg + kk * 32 + qd * 8 + 4);
    }

    for (int ii = 0; ii < 8; ++ii) {
        const float* qm = Qs  + ii * 64;
        const float* qg = Qgs + ii * 64;
        f16x8 am[2], ag[2];
#pragma unroll
        for (int kk = 0; kk < 2; ++kk) {
            int cb = kk * 32 + qd * 8;
            f32x4 qa = *(const f32x4*)(qm + cb);
            f32x4 qb = *(const f32x4*)(qm + cb + 4);
            f32x4 ha = *(const f32x4*)(qg + cb);
            f32x4 hb = *(const f32x4*)(qg + cb + 4);
#pragma unroll
            for (int t = 0; t < 4; ++t) {
                float em0 = pm[kk * 2][t] * qa[t];
                float em1 = pm[kk * 2 + 1][t] * qb[t];
                float eg0 = pg[kk * 2][t] * ha[t];
                float eg1 = pg[kk * 2 + 1][t] * hb[t];
                am[kk][t]     = (_Float16)(1.0f - 2.0f * rcp_f(em0 + 1.0f));
                am[kk][t + 4] = (_Float16)(1.0f - 2.0f * rcp_f(em1 + 1.0f));
                ag[kk][t]     = (_Float16)(1.0f - 2.0f * rcp_f(eg0 + 1.0f));
                ag[kk][t + 4] = (_Float16)(1.0f - 2.0f * rcp_f(eg1 + 1.0f));
            }
        }
#pragma unroll
        for (int cc = 0; cc < 4; ++cc) {
            f32x4 d = {bim[cc], bim[cc], bim[cc], bim[cc]};
            d = __builtin_amdgcn_mfma_f32_16x16x32_f16(am[0], bwm[cc][0], d, 0, 0, 0);
            d = __builtin_amdgcn_mfma_f32_16x16x32_f16(am[1], bwm[cc][1], d, 0, 0, 0);
            f32x4 e = {big[cc], big[cc], big[cc], big[cc]};
            e = __builtin_amdgcn_mfma_f32_16x16x32_f16(ag[0], bwg[cc][0], e, 0, 0, 0);
            e = __builtin_amdgcn_mfma_f32_16x16x32_f16(ag[1], bwg[cc][1], e, 0, 0, 0);
#pragma unroll
            for (int r = 0; r < 4; ++r)
                acc[cc][r] += d[r] * fast_sigmoid(e[r]);
        }
    }

    float* dst = part + (atomic_mode ? (size_t)0 : (size_t)blockIdx.x * S_ELEM)
                 + (size_t)n * 4096;
#pragma unroll
    for (int cc = 0; cc < 4; ++cc)
#pragma unroll
        for (int r = 0; r < 4; ++r) {
            int jo = 16 * w + qd * 4 + r;
            int co = cc * 16 + l16;
            if (atomic_mode) atomicAdd(dst + jo * 64 + co, acc[cc][r]);
            else             dst[jo * 64 + co] = acc[cc][r];
        }
}

// ---------------------------------------------------------------------------
// finalize: out = U * sigmoid(G) + (sum of partials) / 63
// ---------------------------------------------------------------------------
__global__ __launch_bounds__(256) void finalize_kernel(
    const float* __restrict__ U, const float* __restrict__ G,
    const float* __restrict__ part, float* __restrict__ out, int nchunks)
{
    int i = blockIdx.x * 256 + threadIdx.x;   // f32x4 units
    const f32x4* u4 = (const f32x4*)U;
    const f32x4* g4 = (const f32x4*)G;
    const f32x4* p4 = (const f32x4*)part;
    f32x4* o4 = (f32x4*)out;
    f32x4 s = {0.0f, 0.0f, 0.0f, 0.0f};
    for (int ch = 0; ch < nchunks; ++ch)
        s += p4[(size_t)ch * 131072 + i];
    f32x4 u = u4[i], g = g4[i], r;
#pragma unroll
    for (int t = 0; t < 4; ++t)
        r[t] = u[t] * fast_sigmoid(g[t]) + s[t] * (1.0f / 63.0f);
    o4[i] = r;
}

extern "C" void kernel_launch(void* const* d_in, const int* in_sizes, int n_in,
                              void* d_out, int out_size, void* d_ws, size_t ws_size,
                              hipStream_t stream)
{
    (void)in_sizes; (void)n_in; (void)out_size;
    const float* x     = (const float*)d_in[0];
    const float* W_lin = (const float*)d_in[1];
    const float* b_lin = (const float*)d_in[2];
    const float* Wu1   = (const float*)d_in[3];
    const float* bu1   = (const float*)d_in[4];
    const float* Wu2   = (const float*)d_in[5];
    const float* bu2   = (const float*)d_in[6];
    const float* Wug1  = (const float*)d_in[7];
    const float* bug1  = (const float*)d_in[8];
    const float* Wug2  = (const float*)d_in[9];
    const float* bug2  = (const float*)d_in[10];
    const float* Wb1   = (const float*)d_in[11];
    const float* bb1   = (const float*)d_in[12];
    const float* Wb2   = (const float*)d_in[13];
    const float* bb2   = (const float*)d_in[14];
    const float* Wbg1  = (const float*)d_in[15];
    const float* bbg1  = (const float*)d_in[16];
    const float* Wbg2  = (const float*)d_in[17];
    const float* bbg2  = (const float*)d_in[18];

    float*    ws    = (float*)d_ws;
    _Float16* wfrag = (_Float16*)ws;          // 8192 halves = 4096 floats
    float* base = ws + 4096;
    float* h    = base;
    float* EP   = base + 1 * (size_t)S_ELEM;
    float* EQ   = base + 2 * (size_t)S_ELEM;
    float* EPg  = base + 3 * (size_t)S_ELEM;
    float* EQg  = base + 4 * (size_t)S_ELEM;
    float* T1u  = base + 5 * (size_t)S_ELEM;
    float* T1g  = base + 6 * (size_t)S_ELEM;
    float* U    = base + 7 * (size_t)S_ELEM;
    float* G    = base + 8 * (size_t)S_ELEM;
    float* part = base + 9 * (size_t)S_ELEM;  // 8 chunks (or 1 in atomic mode)

    size_t need_full = (4096 + 17 * (size_t)S_ELEM) * 4;
    int atomic_mode = (ws_size >= need_full) ? 0 : 1;

    hipLaunchKernelGGL(swizzle_kernel, dim3(32), dim3(256), 0, stream,
        Wb2, Wbg2, wfrag);
    hipLaunchKernelGGL(prep1_kernel, dim3(128), dim3(256), 0, stream,
        x, W_lin, b_lin, h);
    hipLaunchKernelGGL(prep2_kernel, dim3(128, 6), dim3(256), 0, stream,
        h, Wb1, bb1, Wbg1, bbg1, Wu1, bu1, Wug1, bug1,
        EP, EQ, EPg, EQg, T1u, T1g);
    hipLaunchKernelGGL(prep3_kernel, dim3(128, 2), dim3(256), 0, stream,
        T1u, Wu2, bu2, T1g, Wug2, bug2, U, G);
    if (atomic_mode)
        hipMemsetAsync(part, 0, (size_t)S_ELEM * 4, stream);
    hipLaunchKernelGGL(binary_kernel, dim3(8, 128), dim3(256), 0, stream,
        EP, EQ, EPg, EQg, bb2, bbg2, wfrag, part, atomic_mode);
    hipLaunchKernelGGL(finalize_kernel, dim3(512), dim3(256), 0, stream,
        U, G, part, (float*)d_out, atomic_mode ? 1 : 8);
}

// Round 4
// 134.492 us; speedup vs baseline: 1.3464x; 1.1326x over previous
//
#include <hip/hip_runtime.h>

#define S_ELEM 524288   // N*K*C = 128*64*64
#define WST 72          // f16 LDS row stride (144 B: 16B-aligned, good bank phases)

typedef __attribute__((ext_vector_type(4))) float    f32x4;
typedef __attribute__((ext_vector_type(2))) float    f32x2;
typedef __attribute__((ext_vector_type(8))) _Float16 f16x8;
typedef __attribute__((ext_vector_type(2))) _Float16 f16x2;

__device__ __forceinline__ float rcp_f(float x) { return __builtin_amdgcn_rcpf(x); }
__device__ __forceinline__ float fast_sigmoid(float x) {
    return rcp_f(1.0f + __expf(-x));
}
__device__ __forceinline__ float tanh_exp(float x) {
    return 1.0f - 2.0f * rcp_f(__expf(2.0f * x) + 1.0f);
}

// A-fragment for mfma_f32_16x16x32_f16: lane m=l16 holds k = kk*32 + qd*8 + j
__device__ __forceinline__ void read_afrag(const _Float16* Act, int row, int qd,
                                           f16x8 a[2]) {
    a[0] = *(const f16x8*)(Act + row * WST + qd * 8);
    a[1] = *(const f16x8*)(Act + row * WST + 32 + qd * 8);
}

// B from Wt (transposed weight, Wt[n][k]): lane n=l16 holds k = kk*32+qd*8+j
__device__ __forceinline__ void mfma_gemm(const f16x8 a[2], const _Float16* Wt,
                                          int l16, int qd, f32x4 acc[4]) {
#pragma unroll
    for (int cc = 0; cc < 4; ++cc) {
        const _Float16* wr = Wt + (cc * 16 + l16) * WST + qd * 8;
        f16x8 b0 = *(const f16x8*)(wr);
        f16x8 b1 = *(const f16x8*)(wr + 32);
        acc[cc] = __builtin_amdgcn_mfma_f32_16x16x32_f16(a[0], b0, acc[cc], 0, 0, 0);
        acc[cc] = __builtin_amdgcn_mfma_f32_16x16x32_f16(a[1], b1, acc[cc], 0, 0, 0);
    }
}

__device__ __forceinline__ void stage_weight(const float* __restrict__ W,
                                             _Float16* Wt, int tid) {
#pragma unroll
    for (int i = 0; i < 16; ++i) {
        int idx = tid + i * 256;         // coalesced f32 read, W[k][n]
        int k = idx >> 6, n = idx & 63;
        Wt[n * WST + k] = (_Float16)W[idx];   // transposed scatter (u16)
    }
}

// ---------------------------------------------------------------------------
// fused_prep: blocks 0..127 run the whole per-row prep chain (64 rows each);
// blocks 128..135 swizzle Wb2/Wbg2 into MFMA B-fragment order (f16).
// ---------------------------------------------------------------------------
__global__ __launch_bounds__(256) void fused_prep_kernel(
    const float* __restrict__ x,
    const float* __restrict__ W_lin, const float* __restrict__ b_lin,
    const float* __restrict__ Wu1,  const float* __restrict__ bu1,
    const float* __restrict__ Wu2,  const float* __restrict__ bu2,
    const float* __restrict__ Wug1, const float* __restrict__ bug1,
    const float* __restrict__ Wug2, const float* __restrict__ bug2,
    const float* __restrict__ Wb1,  const float* __restrict__ bb1,
    const float* __restrict__ Wbg1, const float* __restrict__ bbg1,
    const float* __restrict__ Wb2,  const float* __restrict__ Wbg2,
    float* __restrict__ EP,  float* __restrict__ EQ,
    float* __restrict__ EPg, float* __restrict__ EQg,
    float* __restrict__ um,  _Float16* __restrict__ wfrag)
{
    int tid = threadIdx.x;

    if (blockIdx.x >= 128) {   // swizzle duty: 8 blocks x 1024 elems
        int base = (blockIdx.x - 128) * 1024 + tid * 4;
#pragma unroll
        for (int u = 0; u < 4; ++u) {
            int idx = base + u;
            const float* W = (idx < 4096) ? Wb2 : Wbg2;
            int r = idx & 4095;
            int jj = r & 7, l16 = (r >> 3) & 15, qd = (r >> 7) & 3;
            int kk = (r >> 9) & 1, cc = (r >> 10) & 3;
            int k = kk * 32 + qd * 8 + jj, col = cc * 16 + l16;
            wfrag[idx] = (_Float16)W[k * 64 + col];
        }
        return;
    }

    __shared__ _Float16 Wt0[64 * WST], Wt1[64 * WST];
    __shared__ _Float16 Ax[64 * WST], Ah[64 * WST], Au[64 * WST], Agg[64 * WST];

    int w = tid >> 6, l = tid & 63, qd = l >> 4, l16 = l & 15;
    int row0 = blockIdx.x * 64;
    int myrow = 16 * w + l16;                 // A-frag row (LDS-local)
    int orow  = 16 * w + qd * 4;              // C-frag base row (LDS-local)

    // ---- S0: stage x (f16) and W_lin ----
#pragma unroll
    for (int i = 0; i < 8; ++i) {
        int e = tid * 2 + i * 512;
        f32x2 v = *(const f32x2*)(x + (size_t)row0 * 64 + e);
        f16x2 p;
        p[0] = (_Float16)v[0];
        p[1] = (_Float16)v[1];
        *(f16x2*)(Ax + (e >> 6) * WST + (e & 63)) = p;
    }
    stage_weight(W_lin, Wt0, tid);
    __syncthreads();

    f32x4 acc[4];

    // ---- S1: h = x@W_lin + b_lin -> Ah (f16) ----
    {
        f16x8 a[2]; read_afrag(Ax, myrow, qd, a);
#pragma unroll
        for (int cc = 0; cc < 4; ++cc) {
            float bv = b_lin[cc * 16 + l16];
            acc[cc] = (f32x4){bv, bv, bv, bv};
        }
        mfma_gemm(a, Wt0, l16, qd, acc);
#pragma unroll
        for (int cc = 0; cc < 4; ++cc)
#pragma unroll
            for (int r = 0; r < 4; ++r)
                Ah[(orow + r) * WST + cc * 16 + l16] = (_Float16)acc[cc][r];
    }
    stage_weight(Wb1, Wt1, tid);
    __syncthreads();

    f16x8 ah[2]; read_afrag(Ah, myrow, qd, ah);

    // helper macro: one GEMM stage off Ah
#define STAGE(WTBUF, BIAS, NEXT_W, NEXT_BUF, EMIT)                         \
    {                                                                      \
        _Pragma("unroll")                                                  \
        for (int cc = 0; cc < 4; ++cc) {                                   \
            float bv = (BIAS) ? (BIAS)[cc * 16 + l16] : 0.0f;              \
            acc[cc] = (f32x4){bv, bv, bv, bv};                             \
        }                                                                  \
        mfma_gemm(ah, WTBUF, l16, qd, acc);                                \
        EMIT                                                               \
        if (NEXT_W) stage_weight(NEXT_W, NEXT_BUF, tid);                   \
        __syncthreads();                                                   \
    }

#define EMIT_EXP(DST)                                                      \
        _Pragma("unroll")                                                  \
        for (int cc = 0; cc < 4; ++cc)                                     \
            _Pragma("unroll")                                              \
            for (int r = 0; r < 4; ++r)                                    \
                DST[(size_t)(row0 + orow + r) * 64 + cc * 16 + l16] =      \
                    __expf(2.0f * acc[cc][r]);

#define EMIT_TANH(DST)                                                     \
        _Pragma("unroll")                                                  \
        for (int cc = 0; cc < 4; ++cc)                                     \
            _Pragma("unroll")                                              \
            for (int r = 0; r < 4; ++r)                                    \
                DST[(orow + r) * WST + cc * 16 + l16] =                    \
                    (_Float16)tanh_exp(acc[cc][r]);

    STAGE(Wt1, bb1,  Wb1 + 4096,  Wt0, EMIT_EXP(EP))    // S2a: EP
    STAGE(Wt0, (const float*)nullptr, Wbg1, Wt1, EMIT_EXP(EQ))   // S2b: EQ
    STAGE(Wt1, bbg1, Wbg1 + 4096, Wt0, EMIT_EXP(EPg))   // S2c: EPg
    STAGE(Wt0, (const float*)nullptr, Wu1,  Wt1, EMIT_EXP(EQg))  // S2d: EQg
    STAGE(Wt1, bu1,  Wug1, Wt0, EMIT_TANH(Au))          // S2e: T1u
    STAGE(Wt0, bug1, Wu2,  Wt1, EMIT_TANH(Agg))         // S2f: T1g

    // ---- S3a: U = T1u @ Wu2 + bu2 (keep in regs) ----
    f32x4 uacc[4];
    {
        f16x8 au[2]; read_afrag(Au, myrow, qd, au);
#pragma unroll
        for (int cc = 0; cc < 4; ++cc) {
            float bv = bu2[cc * 16 + l16];
            uacc[cc] = (f32x4){bv, bv, bv, bv};
        }
        mfma_gemm(au, Wt1, l16, qd, uacc);
    }
    stage_weight(Wug2, Wt0, tid);
    __syncthreads();

    // ---- S3b: G = T1g @ Wug2 + bug2 ; um = U * sigmoid(G) ----
    {
        f16x8 ag[2]; read_afrag(Agg, myrow, qd, ag);
#pragma unroll
        for (int cc = 0; cc < 4; ++cc) {
            float bv = bug2[cc * 16 + l16];
            acc[cc] = (f32x4){bv, bv, bv, bv};
        }
        mfma_gemm(ag, Wt0, l16, qd, acc);
#pragma unroll
        for (int cc = 0; cc < 4; ++cc)
#pragma unroll
            for (int r = 0; r < 4; ++r)
                um[(size_t)(row0 + orow + r) * 64 + cc * 16 + l16] =
                    uacc[cc][r] * fast_sigmoid(acc[cc][r]);
    }
#undef STAGE
#undef EMIT_EXP
#undef EMIT_TANH
}

// ---------------------------------------------------------------------------
// binary: block = (jchunk of 16 rows, n). 8 waves; wave w handles i in
// [8w, 8w+8). tanh(P+Q) = 1 - 2/(EP*EQ+1). LDS reduce across waves, write
// out = um + sum/63 directly. No partials, no atomics, no finalize.
// ---------------------------------------------------------------------------
__global__ __launch_bounds__(512) void binary_kernel(
    const float* __restrict__ EP,  const float* __restrict__ EQ,
    const float* __restrict__ EPg, const float* __restrict__ EQg,
    const float* __restrict__ bb2, const float* __restrict__ bbg2,
    const _Float16* __restrict__ wfrag,
    const float* __restrict__ um, float* __restrict__ out)
{
    __shared__ float Qb[8192];           // Qs | Qgs ; Red overlays after sync
    float* Qs  = Qb;
    float* Qgs = Qb + 4096;

    int tid = threadIdx.x, w = tid >> 6, l = tid & 63;
    int qd = l >> 4, l16 = l & 15;
    int n = blockIdx.y, j0 = blockIdx.x * 16;

    const float* EQn  = EQ  + (size_t)n * 4096;
    const float* EQgn = EQg + (size_t)n * 4096;
    for (int idx = tid * 4; idx < 4096; idx += 2048) {
        *(f32x4*)(Qs + idx)  = *(const f32x4*)(EQn + idx);
        *(f32x4*)(Qgs + idx) = *(const f32x4*)(EQgn + idx);
    }

    // P fragments straight from global (16 rows, L1-shared across 8 waves)
    const float* Pr  = EP  + (size_t)n * 4096 + (j0 + l16) * 64;
    const float* Pgr = EPg + (size_t)n * 4096 + (j0 + l16) * 64;
    f32x4 pm[4], pg[4];
    pm[0] = *(const f32x4*)(Pr + qd * 8);
    pm[1] = *(const f32x4*)(Pr + qd * 8 + 4);
    pm[2] = *(const f32x4*)(Pr + 32 + qd * 8);
    pm[3] = *(const f32x4*)(Pr + 32 + qd * 8 + 4);
    pg[0] = *(const f32x4*)(Pgr + qd * 8);
    pg[1] = *(const f32x4*)(Pgr + qd * 8 + 4);
    pg[2] = *(const f32x4*)(Pgr + 32 + qd * 8);
    pg[3] = *(const f32x4*)(Pgr + 32 + qd * 8 + 4);

    const f16x8* wf = (const f16x8*)wfrag;
    f16x8 bwm[4][2], bwg[4][2];
#pragma unroll
    for (int cc = 0; cc < 4; ++cc)
#pragma unroll
        for (int kk = 0; kk < 2; ++kk) {
            bwm[cc][kk] = wf[cc * 128 + kk * 64 + qd * 16 + l16];
            bwg[cc][kk] = wf[512 + cc * 128 + kk * 64 + qd * 16 + l16];
        }
    float bim[4], big[4];
#pragma unroll
    for (int cc = 0; cc < 4; ++cc) {
        bim[cc] = bb2[cc * 16 + l16];
        big[cc] = bbg2[cc * 16 + l16];
    }
    f32x4 acc[4];
#pragma unroll
    for (int cc = 0; cc < 4; ++cc) acc[cc] = (f32x4){0.f, 0.f, 0.f, 0.f};
    __syncthreads();

    for (int ii = 8 * w; ii < 8 * w + 8; ++ii) {
        const float* qm = Qs  + ii * 64;
        const float* qg = Qgs + ii * 64;
        f16x8 am[2], ag[2];
#pragma unroll
        for (int kk = 0; kk < 2; ++kk) {
            int cb = kk * 32 + qd * 8;
            f32x4 qa = *(const f32x4*)(qm + cb);
            f32x4 qb = *(const f32x4*)(qm + cb + 4);
            f32x4 ha = *(const f32x4*)(qg + cb);
            f32x4 hb = *(const f32x4*)(qg + cb + 4);
#pragma unroll
            for (int t = 0; t < 4; ++t) {
                am[kk][t]     = (_Float16)(1.0f - 2.0f * rcp_f(__builtin_fmaf(pm[kk*2][t],   qa[t], 1.0f)));
                am[kk][t + 4] = (_Float16)(1.0f - 2.0f * rcp_f(__builtin_fmaf(pm[kk*2+1][t], qb[t], 1.0f)));
                ag[kk][t]     = (_Float16)(1.0f - 2.0f * rcp_f(__builtin_fmaf(pg[kk*2][t],   ha[t], 1.0f)));
                ag[kk][t + 4] = (_Float16)(1.0f - 2.0f * rcp_f(__builtin_fmaf(pg[kk*2+1][t], hb[t], 1.0f)));
            }
        }
#pragma unroll
        for (int cc = 0; cc < 4; ++cc) {
            f32x4 d = {bim[cc], bim[cc], bim[cc], bim[cc]};
            d = __builtin_amdgcn_mfma_f32_16x16x32_f16(am[0], bwm[cc][0], d, 0, 0, 0);
            d = __builtin_amdgcn_mfma_f32_16x16x32_f16(am[1], bwm[cc][1], d, 0, 0, 0);
            f32x4 e = {big[cc], big[cc], big[cc], big[cc]};
            e = __builtin_amdgcn_mfma_f32_16x16x32_f16(ag[0], bwg[cc][0], e, 0, 0, 0);
            e = __builtin_amdgcn_mfma_f32_16x16x32_f16(ag[1], bwg[cc][1], e, 0, 0, 0);
#pragma unroll
            for (int r = 0; r < 4; ++r)
                acc[cc][r] += d[r] * fast_sigmoid(e[r]);
        }
    }

    __syncthreads();                      // all Qs reads done; reuse as Red
    float* Red = Qb;
#pragma unroll
    for (int cc = 0; cc < 4; ++cc)
#pragma unroll
        for (int r = 0; r < 4; ++r)
            Red[w * 1024 + (qd * 4 + r) * 64 + cc * 16 + l16] = acc[cc][r];
    __syncthreads();

    {
        int flat = tid * 2;               // 512 threads x 2 elems = 1024
        f32x2 s = {0.f, 0.f};
#pragma unroll
        for (int ww = 0; ww < 8; ++ww)
            s += *(const f32x2*)(Red + ww * 1024 + flat);
        int row = flat >> 6, col = flat & 63;
        size_t g = (size_t)n * 4096 + (size_t)(j0 + row) * 64 + col;
        f32x2 u = *(const f32x2*)(um + g);
        f32x2 o;
        o[0] = u[0] + s[0] * (1.0f / 63.0f);
        o[1] = u[1] + s[1] * (1.0f / 63.0f);
        *(f32x2*)(out + g) = o;
    }
}

extern "C" void kernel_launch(void* const* d_in, const int* in_sizes, int n_in,
                              void* d_out, int out_size, void* d_ws, size_t ws_size,
                              hipStream_t stream)
{
    (void)in_sizes; (void)n_in; (void)out_size; (void)ws_size;
    const float* x     = (const float*)d_in[0];
    const float* W_lin = (const float*)d_in[1];
    const float* b_lin = (const float*)d_in[2];
    const float* Wu1   = (const float*)d_in[3];
    const float* bu1   = (const float*)d_in[4];
    const float* Wu2   = (const float*)d_in[5];
    const float* bu2   = (const float*)d_in[6];
    const float* Wug1  = (const float*)d_in[7];
    const float* bug1  = (const float*)d_in[8];
    const float* Wug2  = (const float*)d_in[9];
    const float* bug2  = (const float*)d_in[10];
    const float* Wb1   = (const float*)d_in[11];
    const float* bb1   = (const float*)d_in[12];
    const float* Wb2   = (const float*)d_in[13];
    const float* bb2   = (const float*)d_in[14];
    const float* Wbg1  = (const float*)d_in[15];
    const float* bbg1  = (const float*)d_in[16];
    const float* Wbg2  = (const float*)d_in[17];
    const float* bbg2  = (const float*)d_in[18];

    float*    ws    = (float*)d_ws;
    _Float16* wfrag = (_Float16*)ws;          // 8192 f16 = 16 KB = 4096 floats
    float* base = ws + 4096;
    float* EP   = base;
    float* EQ   = base + 1 * (size_t)S_ELEM;
    float* EPg  = base + 2 * (size_t)S_ELEM;
    float* EQg  = base + 3 * (size_t)S_ELEM;
    float* um   = base + 4 * (size_t)S_ELEM;

    hipLaunchKernelGGL(fused_prep_kernel, dim3(136), dim3(256), 0, stream,
        x, W_lin, b_lin, Wu1, bu1, Wu2, bu2, Wug1, bug1, Wug2, bug2,
        Wb1, bb1, Wbg1, bbg1, Wb2, Wbg2,
        EP, EQ, EPg, EQg, um, wfrag);
    hipLaunchKernelGGL(binary_kernel, dim3(4, 128), dim3(512), 0, stream,
        EP, EQ, EPg, EQg, bb2, bbg2, wfrag, um, (float*)d_out);
}

// Round 5
// 116.689 us; speedup vs baseline: 1.5518x; 1.1526x over previous
//
#include <hip/hip_runtime.h>

#define WST 72   // f16 LDS row stride (144 B = 9*16: aligned, benign banks)

typedef __attribute__((ext_vector_type(4))) float    f32x4;
typedef __attribute__((ext_vector_type(2))) float    f32x2;
typedef __attribute__((ext_vector_type(8))) _Float16 f16x8;
typedef __attribute__((ext_vector_type(2))) _Float16 f16x2;

__device__ __forceinline__ float rcp_f(float x) { return __builtin_amdgcn_rcpf(x); }
__device__ __forceinline__ float fast_sigmoid(float x) {
    return rcp_f(1.0f + __expf(-x));
}
__device__ __forceinline__ float tanh_exp(float x) {
    return 1.0f - 2.0f * rcp_f(__expf(2.0f * x) + 1.0f);
}

// stage 64x64 f32 weight W[k][n] -> LDS transposed f16 Wt[n*WST+k], 512 thr
__device__ __forceinline__ void stage512(const float* __restrict__ W,
                                         _Float16* Wt, int tid) {
#pragma unroll
    for (int i = 0; i < 8; ++i) {
        int idx = tid + i * 512;
        int k = idx >> 6, c = idx & 63;
        Wt[c * WST + k] = (_Float16)W[idx];
    }
}

// one 16x16(x64) strip of a 64x64x64 GEMM: wave covers rows [arow16),
// cols [colb, colb+16) and [colb+16, colb+32). acc pre-loaded with bias.
__device__ __forceinline__ void gemm2(const _Float16* Act, int arow, int qd,
                                      const _Float16* Wt, int colb,
                                      f32x4 acc[2]) {
    f16x8 a0 = *(const f16x8*)(Act + arow * WST + qd * 8);
    f16x8 a1 = *(const f16x8*)(Act + arow * WST + 32 + qd * 8);
#pragma unroll
    for (int cc = 0; cc < 2; ++cc) {
        const _Float16* wr = Wt + (colb + cc * 16) * WST + qd * 8;
        f16x8 b0 = *(const f16x8*)(wr);
        f16x8 b1 = *(const f16x8*)(wr + 32);
        acc[cc] = __builtin_amdgcn_mfma_f32_16x16x32_f16(a0, b0, acc[cc], 0, 0, 0);
        acc[cc] = __builtin_amdgcn_mfma_f32_16x16x32_f16(a1, b1, acc[cc], 0, 0, 0);
    }
}

// ---------------------------------------------------------------------------
// fused_all: block = (n, j-half). Prep chain for n in LDS, then binary path
// for 32 j-rows, reduce, write out. Zero global intermediates.
// ---------------------------------------------------------------------------
__global__ __launch_bounds__(512, 2) void fused_all_kernel(
    const float* __restrict__ x,
    const float* __restrict__ W_lin, const float* __restrict__ b_lin,
    const float* __restrict__ Wu1,  const float* __restrict__ bu1,
    const float* __restrict__ Wu2,  const float* __restrict__ bu2,
    const float* __restrict__ Wug1, const float* __restrict__ bug1,
    const float* __restrict__ Wug2, const float* __restrict__ bug2,
    const float* __restrict__ Wb1,  const float* __restrict__ bb1,
    const float* __restrict__ Wb2,  const float* __restrict__ bb2,
    const float* __restrict__ Wbg1, const float* __restrict__ bbg1,
    const float* __restrict__ Wbg2, const float* __restrict__ bbg2,
    float* __restrict__ out)
{
    __shared__ __align__(16) char smem[113664];
    _Float16* Wt0  = (_Float16*)(smem);            // 9216   -> Red
    _Float16* Wt1  = (_Float16*)(smem + 9216);     // 9216   (Wb2t in binary) -> Red
    _Float16* Ax   = (_Float16*)(smem + 18432);    // 9216   -> Red
    _Float16* Ah   = (_Float16*)(smem + 27648);    // 9216   -> Red
    _Float16* Au   = (_Float16*)(smem + 36864);    // 9216   (Wbg2t in binary)
    _Float16* Agg  = (_Float16*)(smem + 46080);    // 9216
    float*    EQb  = (float*)(smem + 55296);       // 16384  (64x64 f32)
    float*    EQgb = (float*)(smem + 71680);       // 16384
    float*    EPm  = (float*)(smem + 88064);       // 8704   (32x68 f32)
    float*    EPgm = (float*)(smem + 96768);       // 8704
    float*    um32 = (float*)(smem + 105472);      // 8192   (32x64 f32)
    float*    Red  = (float*)(smem);               // 32768 alias Wt0..Ah

    int tid = threadIdx.x, w = tid >> 6, l = tid & 63;
    int qd = l >> 4, l16 = l & 15;
    int n = blockIdx.x >> 1, jsel = blockIdx.x & 1;

    // prep-phase wave mapping: 4 row-quarters x 2 col-halves
    int rw = w & 3, ch = w >> 2;
    int arow = rw * 16 + l16;           // A-frag row
    int colb = ch * 32 + l16;           // + cc*16 -> C col
    int crow = rw * 16 + qd * 4;        // + r     -> C row
    bool mine = (rw >> 1) == jsel;      // wave-uniform
    int lr0 = (rw & 1) * 16 + qd * 4;   // local row in the 32-row j-set

    f32x4 acc[2];

    // ---- S0: stage x -> Ax (f16), W_lin -> Wt0 ----
#pragma unroll
    for (int i = 0; i < 4; ++i) {
        int e = tid * 2 + i * 1024;
        f32x2 v = *(const f32x2*)(x + (size_t)n * 4096 + e);
        f16x2 p; p[0] = (_Float16)v[0]; p[1] = (_Float16)v[1];
        *(f16x2*)(Ax + (e >> 6) * WST + (e & 63)) = p;
    }
    stage512(W_lin, Wt0, tid);
    __syncthreads();

    // ---- S1: h = x@W_lin + b_lin -> Ah ----
#pragma unroll
    for (int cc = 0; cc < 2; ++cc) {
        float bv = b_lin[colb + cc * 16];
        acc[cc] = (f32x4){bv, bv, bv, bv};
    }
    gemm2(Ax, arow, qd, Wt0, colb, acc);
#pragma unroll
    for (int cc = 0; cc < 2; ++cc)
#pragma unroll
        for (int r = 0; r < 4; ++r)
            Ah[(crow + r) * WST + colb + cc * 16] = (_Float16)acc[cc][r];
    stage512(Wb1, Wt1, tid);            // P-part of Wb1
    __syncthreads();

    // ---- S2: EP = exp(2(h@Wb1[:C]+bb1)) -> EPm (own 32 rows) ----
#pragma unroll
    for (int cc = 0; cc < 2; ++cc) {
        float bv = bb1[colb + cc * 16];
        acc[cc] = (f32x4){bv, bv, bv, bv};
    }
    gemm2(Ah, arow, qd, Wt1, colb, acc);
    if (mine) {
#pragma unroll
        for (int cc = 0; cc < 2; ++cc)
#pragma unroll
            for (int r = 0; r < 4; ++r)
                EPm[(lr0 + r) * 68 + colb + cc * 16] = __expf(2.0f * acc[cc][r]);
    }
    stage512(Wb1 + 4096, Wt0, tid);     // Q-part of Wb1
    __syncthreads();

    // ---- S3: EQ = exp(2(h@Wb1[C:])) -> EQb (full 64 rows) ----
    acc[0] = (f32x4){0.f, 0.f, 0.f, 0.f};
    acc[1] = (f32x4){0.f, 0.f, 0.f, 0.f};
    gemm2(Ah, arow, qd, Wt0, colb, acc);
#pragma unroll
    for (int cc = 0; cc < 2; ++cc)
#pragma unroll
        for (int r = 0; r < 4; ++r)
            EQb[(crow + r) * 64 + colb + cc * 16] = __expf(2.0f * acc[cc][r]);
    stage512(Wbg1, Wt1, tid);
    __syncthreads();

    // ---- S4: EPg -> EPgm ----
#pragma unroll
    for (int cc = 0; cc < 2; ++cc) {
        float bv = bbg1[colb + cc * 16];
        acc[cc] = (f32x4){bv, bv, bv, bv};
    }
    gemm2(Ah, arow, qd, Wt1, colb, acc);
    if (mine) {
#pragma unroll
        for (int cc = 0; cc < 2; ++cc)
#pragma unroll
            for (int r = 0; r < 4; ++r)
                EPgm[(lr0 + r) * 68 + colb + cc * 16] = __expf(2.0f * acc[cc][r]);
    }
    stage512(Wbg1 + 4096, Wt0, tid);
    __syncthreads();

    // ---- S5: EQg -> EQgb ----
    acc[0] = (f32x4){0.f, 0.f, 0.f, 0.f};
    acc[1] = (f32x4){0.f, 0.f, 0.f, 0.f};
    gemm2(Ah, arow, qd, Wt0, colb, acc);
#pragma unroll
    for (int cc = 0; cc < 2; ++cc)
#pragma unroll
        for (int r = 0; r < 4; ++r)
            EQgb[(crow + r) * 64 + colb + cc * 16] = __expf(2.0f * acc[cc][r]);
    stage512(Wu1, Wt1, tid);
    __syncthreads();

    // ---- S6: T1u = tanh(h@Wu1+bu1) -> Au ----
#pragma unroll
    for (int cc = 0; cc < 2; ++cc) {
        float bv = bu1[colb + cc * 16];
        acc[cc] = (f32x4){bv, bv, bv, bv};
    }
    gemm2(Ah, arow, qd, Wt1, colb, acc);
#pragma unroll
    for (int cc = 0; cc < 2; ++cc)
#pragma unroll
        for (int r = 0; r < 4; ++r)
            Au[(crow + r) * WST + colb + cc * 16] = (_Float16)tanh_exp(acc[cc][r]);
    stage512(Wug1, Wt0, tid);
    __syncthreads();

    // ---- S7: T1g = tanh(h@Wug1+bug1) -> Agg ----
#pragma unroll
    for (int cc = 0; cc < 2; ++cc) {
        float bv = bug1[colb + cc * 16];
        acc[cc] = (f32x4){bv, bv, bv, bv};
    }
    gemm2(Ah, arow, qd, Wt0, colb, acc);
#pragma unroll
    for (int cc = 0; cc < 2; ++cc)
#pragma unroll
        for (int r = 0; r < 4; ++r)
            Agg[(crow + r) * WST + colb + cc * 16] = (_Float16)tanh_exp(acc[cc][r]);
    stage512(Wu2, Wt1, tid);
    __syncthreads();

    // ---- S8: U = T1u@Wu2 + bu2 (keep in regs) ----
    f32x4 uacc[2];
#pragma unroll
    for (int cc = 0; cc < 2; ++cc) {
        float bv = bu2[colb + cc * 16];
        uacc[cc] = (f32x4){bv, bv, bv, bv};
    }
    gemm2(Au, arow, qd, Wt1, colb, uacc);
    stage512(Wug2, Wt0, tid);
    __syncthreads();

    // ---- S9: G = T1g@Wug2 + bug2 ; um = U*sigmoid(G) -> um32 (own rows)
    //          + stage Wb2 -> Wt1, Wbg2 -> Au (both dead now) ----
#pragma unroll
    for (int cc = 0; cc < 2; ++cc) {
        float bv = bug2[colb + cc * 16];
        acc[cc] = (f32x4){bv, bv, bv, bv};
    }
    gemm2(Agg, arow, qd, Wt0, colb, acc);
    if (mine) {
#pragma unroll
        for (int cc = 0; cc < 2; ++cc)
#pragma unroll
            for (int r = 0; r < 4; ++r)
                um32[(lr0 + r) * 64 + colb + cc * 16] =
                    uacc[cc][r] * fast_sigmoid(acc[cc][r]);
    }
    stage512(Wb2, Wt1, tid);
    stage512(Wbg2, Au, tid);
    __syncthreads();

    // =============== binary phase ===============
    int jgrp = w >> 2, iw = w & 3;      // 2 j-groups x 4 i-ranges

    // B fragments (all 64 cols) from transposed weights in LDS
    f16x8 bwm[4][2], bwg[4][2];
#pragma unroll
    for (int cc = 0; cc < 4; ++cc)
#pragma unroll
        for (int kk = 0; kk < 2; ++kk) {
            bwm[cc][kk] = *(const f16x8*)(Wt1 + (cc * 16 + l16) * WST + kk * 32 + qd * 8);
            bwg[cc][kk] = *(const f16x8*)(Au  + (cc * 16 + l16) * WST + kk * 32 + qd * 8);
        }
    float bim[4], big[4];
#pragma unroll
    for (int cc = 0; cc < 4; ++cc) {
        bim[cc] = bb2[cc * 16 + l16];
        big[cc] = bbg2[cc * 16 + l16];
    }

    // P fragments (loop-invariant, register-resident)
    const float* pr  = EPm  + (jgrp * 16 + l16) * 68;
    const float* pgr = EPgm + (jgrp * 16 + l16) * 68;
    f32x4 pm[4], pg[4];
    pm[0] = *(const f32x4*)(pr + qd * 8);
    pm[1] = *(const f32x4*)(pr + qd * 8 + 4);
    pm[2] = *(const f32x4*)(pr + 32 + qd * 8);
    pm[3] = *(const f32x4*)(pr + 32 + qd * 8 + 4);
    pg[0] = *(const f32x4*)(pgr + qd * 8);
    pg[1] = *(const f32x4*)(pgr + qd * 8 + 4);
    pg[2] = *(const f32x4*)(pgr + 32 + qd * 8);
    pg[3] = *(const f32x4*)(pgr + 32 + qd * 8 + 4);

    f32x4 bacc[4];
#pragma unroll
    for (int cc = 0; cc < 4; ++cc) bacc[cc] = (f32x4){0.f, 0.f, 0.f, 0.f};

    for (int ii = iw * 16; ii < iw * 16 + 16; ++ii) {
        const float* qm = EQb  + ii * 64;
        const float* qg = EQgb + ii * 64;
        f16x8 am[2], ag[2];
#pragma unroll
        for (int kk = 0; kk < 2; ++kk) {
            int cb = kk * 32 + qd * 8;
            f32x4 qa = *(const f32x4*)(qm + cb);
            f32x4 qb = *(const f32x4*)(qm + cb + 4);
            f32x4 ha = *(const f32x4*)(qg + cb);
            f32x4 hb = *(const f32x4*)(qg + cb + 4);
#pragma unroll
            for (int t = 0; t < 4; ++t) {
                am[kk][t]     = (_Float16)(1.0f - 2.0f * rcp_f(__builtin_fmaf(pm[kk*2][t],   qa[t], 1.0f)));
                am[kk][t + 4] = (_Float16)(1.0f - 2.0f * rcp_f(__builtin_fmaf(pm[kk*2+1][t], qb[t], 1.0f)));
                ag[kk][t]     = (_Float16)(1.0f - 2.0f * rcp_f(__builtin_fmaf(pg[kk*2][t],   ha[t], 1.0f)));
                ag[kk][t + 4] = (_Float16)(1.0f - 2.0f * rcp_f(__builtin_fmaf(pg[kk*2+1][t], hb[t], 1.0f)));
            }
        }
#pragma unroll
        for (int cc = 0; cc < 4; ++cc) {
            f32x4 d = {bim[cc], bim[cc], bim[cc], bim[cc]};
            d = __builtin_amdgcn_mfma_f32_16x16x32_f16(am[0], bwm[cc][0], d, 0, 0, 0);
            d = __builtin_amdgcn_mfma_f32_16x16x32_f16(am[1], bwm[cc][1], d, 0, 0, 0);
            f32x4 e = {big[cc], big[cc], big[cc], big[cc]};
            e = __builtin_amdgcn_mfma_f32_16x16x32_f16(ag[0], bwg[cc][0], e, 0, 0, 0);
            e = __builtin_amdgcn_mfma_f32_16x16x32_f16(ag[1], bwg[cc][1], e, 0, 0, 0);
#pragma unroll
            for (int r = 0; r < 4; ++r)
                bacc[cc][r] += d[r] * fast_sigmoid(e[r]);
        }
    }

    __syncthreads();   // everyone done with Wt1/Au B-frag reads & loop
#pragma unroll
    for (int cc = 0; cc < 4; ++cc)
#pragma unroll
        for (int r = 0; r < 4; ++r)
            Red[(jgrp * 4 + iw) * 1024 + (qd * 4 + r) * 64 + cc * 16 + l16] = bacc[cc][r];
    __syncthreads();

    // reduce 4 i-ranges, add unary, write out
    {
        int e = tid * 4;                 // 512 thr x 4 = 2048 = 32x64
        int lr = e >> 6, col = e & 63;
        int g = lr >> 4, rr = lr & 15;
        f32x4 s = {0.f, 0.f, 0.f, 0.f};
#pragma unroll
        for (int w2 = 0; w2 < 4; ++w2)
            s += *(const f32x4*)(Red + (g * 4 + w2) * 1024 + rr * 64 + col);
        f32x4 u = *(const f32x4*)(um32 + lr * 64 + col);
        f32x4 o;
#pragma unroll
        for (int t = 0; t < 4; ++t)
            o[t] = u[t] + s[t] * (1.0f / 63.0f);
        *(f32x4*)(out + (size_t)n * 4096 + (size_t)(jsel * 32 + lr) * 64 + col) = o;
    }
}

extern "C" void kernel_launch(void* const* d_in, const int* in_sizes, int n_in,
                              void* d_out, int out_size, void* d_ws, size_t ws_size,
                              hipStream_t stream)
{
    (void)in_sizes; (void)n_in; (void)out_size; (void)d_ws; (void)ws_size;
    const float* x     = (const float*)d_in[0];
    const float* W_lin = (const float*)d_in[1];
    const float* b_lin = (const float*)d_in[2];
    const float* Wu1   = (const float*)d_in[3];
    const float* bu1   = (const float*)d_in[4];
    const float* Wu2   = (const float*)d_in[5];
    const float* bu2   = (const float*)d_in[6];
    const float* Wug1  = (const float*)d_in[7];
    const float* bug1  = (const float*)d_in[8];
    const float* Wug2  = (const float*)d_in[9];
    const float* bug2  = (const float*)d_in[10];
    const float* Wb1   = (const float*)d_in[11];
    const float* bb1   = (const float*)d_in[12];
    const float* Wb2   = (const float*)d_in[13];
    const float* bb2   = (const float*)d_in[14];
    const float* Wbg1  = (const float*)d_in[15];
    const float* bbg1  = (const float*)d_in[16];
    const float* Wbg2  = (const float*)d_in[17];
    const float* bbg2  = (const float*)d_in[18];

    hipLaunchKernelGGL(fused_all_kernel, dim3(256), dim3(512), 0, stream,
        x, W_lin, b_lin, Wu1, bu1, Wu2, bu2, Wug1, bug1, Wug2, bug2,
        Wb1, bb1, Wb2, bb2, Wbg1, bbg1, Wbg2, bbg2,
        (float*)d_out);
}